// Round 9
// baseline (576.894 us; speedup 1.0000x reference)
//
#include <hip/hip_runtime.h>

#define BB 128
#define TT 512
#define CC 128

typedef short short8 __attribute__((ext_vector_type(8)));
typedef float f32x4  __attribute__((ext_vector_type(4)));
typedef unsigned u32x4 __attribute__((ext_vector_type(4)));

__device__ __forceinline__ unsigned pk_trunc(float a, float b) {
    // lo16 = trunc-bf16(a), hi16 = trunc-bf16(b); single v_perm (R5-verified)
    return __builtin_amdgcn_perm(__float_as_uint(a), __float_as_uint(b), 0x03020706u);
}
__device__ __forceinline__ unsigned short f2bf(float f) {   // RNE (E setup only)
    unsigned u = __float_as_uint(f);
    u += 0x7fffu + ((u >> 16) & 1u);
    return (unsigned short)(u >> 16);
}
__device__ __forceinline__ float lo16f(unsigned u) { return __uint_as_float(u << 16); }
__device__ __forceinline__ float hi16f(unsigned u) { return __uint_as_float(u & 0xffff0000u); }

// Barrier that drains ONLY LDS ops (ds_write visibility) and leaves the
// loaders' global loads in flight (no vmcnt drain — the m97 stall mode).
__device__ __forceinline__ void barrier_lgkm() {
    asm volatile("s_waitcnt lgkmcnt(0)" ::: "memory");
    __builtin_amdgcn_s_barrier();
}

#define MFMA16(A, B, C) __builtin_amdgcn_mfma_f32_16x16x32_bf16((A), (B), (C), 0, 0, 0)

// ---------------------------------------------------------------------------
// One fused kernel, 512 threads (8 waves) per block.
// Blocks 0..7  : scan group g (16 batches). Waves 0-3 = MFMA consumers
//                (wave w owns output tiles {w, w+4} = 32 columns); waves 4-7 =
//                loaders (turn t%4) streaming bf16-packed exp(y_pred*mask)
//                (-1 sentinel when masked) into an 8-step LDS ring.
//                ALL 8 waves run the same t-loop with ONE lgkm-only barrier
//                per step; loader global loads span 4 steps in flight.
// Blocks 8..135: real-path score, 8 waves x 64 rows; atomicAdd(-score).
// ---------------------------------------------------------------------------
__global__ __launch_bounds__(512, 1) void crf_all(
    const float* __restrict__ y_true, const float* __restrict__ y_pred,
    const float* __restrict__ mask, const float* __restrict__ trans,
    float* __restrict__ out)
{
    __shared__ __align__(16) unsigned ring[8][1024];  // 32 KB: 8 step slots x 4 KB
    __shared__ __align__(16) unsigned st[2][1024];    // 8 KB: packed state, dbuf
    __shared__ float fsum[4][16];

    const int tid  = threadIdx.x;
    const int lane = tid & 63;
    const int w    = tid >> 6;

    if (blockIdx.x >= 8) {
        // ===================== real path (R3..R8-verified core) =============
        const int rb = blockIdx.x - 8;
        const int ts = w * 64;
        const int te = min(ts + 64, TT - 1);   // +1 overlap row
        const float* yt_b = y_true + (size_t)rb * TT * CC;
        const float* yp_b = y_pred + (size_t)rb * TT * CC;
        const float* m_b  = mask + (size_t)rb * TT;

        float em = 0.f, tr = 0.f;
        int lprev = 0; float mprev = 0.f;
        const float* ytr = yt_b + ts * CC;
        const float* ypr = yp_b + ts * CC;
        float cyt0 = ytr[lane], cyt1 = ytr[lane + 64];
        float cyp0 = ypr[lane], cyp1 = ypr[lane + 64];
        float cm = m_b[ts];
        for (int t = ts; t <= te; ++t) {
            float nyt0 = 0.f, nyt1 = 0.f, nyp0 = 0.f, nyp1 = 0.f, nm = 0.f;
            if (t < te) {
                const float* ytn = yt_b + (t + 1) * CC;
                const float* ypn = yp_b + (t + 1) * CC;
                nyt0 = ytn[lane]; nyt1 = ytn[lane + 64];
                nyp0 = ypn[lane]; nyp1 = ypn[lane + 64];
                nm = m_b[t + 1];
            }
            unsigned long long b0 = __ballot(cyt0 > 0.5f);
            unsigned long long b1 = __ballot(cyt1 > 0.5f);
            int l = b0 ? (__ffsll(b0) - 1) : (64 + __ffsll(b1) - 1);
            float v0 = __shfl(cyp0, l & 63);
            float v1 = __shfl(cyp1, l & 63);
            float v  = (l < 64) ? v0 : v1;
            if (lane == 0) {
                if (t < ts + 64) em += cm * cm * v;
                if (t > ts)      tr += mprev * cm * trans[lprev * CC + l];
            }
            lprev = l; mprev = cm;
            cyt0 = nyt0; cyt1 = nyt1; cyp0 = nyp0; cyp1 = nyp1; cm = nm;
        }
        if (lane == 0) atomicAdd(&out[rb], -(em + tr));
        return;
    }

    // ========================== scan blocks ==========================
    const int g  = blockIdx.x;
    const int bq = lane & 15;
    const int q  = lane >> 4;

    if (w >= 4) {
        // ===================== loader wave (p = w-4) =====================
        const int p = w - 4;                      // produces steps s ≡ p (mod 4)
        const float* ybase = y_pred + (size_t)(g * 16 + bq) * TT * CC;
        const float* mrow  = mask + (size_t)(g * 16 + bq) * TT;

        float4 va[8]; float ma;
        auto ldrow = [&](int s) {
            const float* r = ybase + (size_t)s * CC;
            #pragma unroll
            for (int c = 0; c < 8; ++c)
                va[c] = *(const float4*)(r + ((c >> 1) * 32 + q * 8 + (c & 1) * 4));
            ma = mrow[s];
        };
        auto produce = [&](int s) {               // pack + ds_write slot s
            const bool live = (ma > 0.f) || (s == 0);
            unsigned pu[16];
            #pragma unroll
            for (int c = 0; c < 8; ++c) {
                float ex, ey, ez, ew;
                if (live) {
                    ex = __expf(va[c].x * ma); ey = __expf(va[c].y * ma);
                    ez = __expf(va[c].z * ma); ew = __expf(va[c].w * ma);
                } else { ex = ey = ez = ew = -1.0f; }
                pu[2 * c + 0] = pk_trunc(ex, ey);
                pu[2 * c + 1] = pk_trunc(ez, ew);
            }
            unsigned* dst = &ring[s & 7][0];
            #pragma unroll
            for (int k = 0; k < 4; ++k) {
                u32x4 wv;
                wv[0] = pu[4 * k + 0]; wv[1] = pu[4 * k + 1];
                wv[2] = pu[4 * k + 2]; wv[3] = pu[4 * k + 3];
                *(u32x4*)(dst + k * 256 + lane * 4) = wv;
            }
        };

        // prologue: synchronously produce s = p and p+4 (slots 0..7 across the
        // 4 loaders), then issue loads for s = p+8 (written at turn t = p+4).
        ldrow(p);     produce(p);
        ldrow(p + 4); produce(p + 4);
        ldrow(p + 8);

        barrier_lgkm();                           // A: ring slots 0..7 ready
        barrier_lgkm();                           // B: consumer init done
        for (int t = 1; t < TT; ++t) {
            if (((t & 3) == p) && (t >= p + 4) && (t + 4 < TT)) {
                produce(t + 4);                   // data loaded 4 steps ago
                if (t + 8 < TT) ldrow(t + 8);     // stays in flight 4 steps
            }
            barrier_lgkm();
        }
        return;
    }

    // ===================== consumer wave (w = 0..3) =====================
    // A-frags: tiles nt ∈ {w, w+4} of E^T with row perm sigma (R4-verified).
    short8 Af[2][4];
    #pragma unroll
    for (int ii = 0; ii < 2; ++ii) {
        const int nt = w + 4 * ii;
        const int j = 32 * (nt & 3) + 8 * (bq >> 2) + 4 * (nt >> 2) + (bq & 3);
        #pragma unroll
        for (int kt = 0; kt < 4; ++kt) {
            #pragma unroll
            for (int e = 0; e < 8; ++e)
                Af[ii][kt][e] = (short)f2bf(__expf(trans[(kt * 32 + q * 8 + e) * CC + j]));
        }
    }

    float lacc = 0.f;
    const int soff = w * 256 + lane * 4;          // this wave's state quad

    barrier_lgkm();                               // A: ring slots 0..7 ready
    // t=0 init: state quad w = e(0) quad w (ring packing == state packing)
    *(u32x4*)&st[0][soff] = *(const u32x4*)&ring[0][soff];
    barrier_lgkm();                               // B

    for (int t = 1; t < TT; ++t) {
        const int rp = (t - 1) & 1;
        u32x4 B0 = *(const u32x4*)&st[rp][  0 + lane * 4];
        u32x4 B1 = *(const u32x4*)&st[rp][256 + lane * 4];
        u32x4 B2 = *(const u32x4*)&st[rp][512 + lane * 4];
        u32x4 B3 = *(const u32x4*)&st[rp][768 + lane * 4];
        u32x4 Ew = *(const u32x4*)&ring[t & 7][soff];

        float pendl = 1.f;
        const bool AP = ((t & 3) == 1) && (t > 1);
        if (AP) {                                  // renorm of state after t-1
            float sc = __shfl(lo16f(B0[0]), bq, 64);   // S[b][0], q=0 lanes
            pendl = __builtin_amdgcn_rcpf(sc);
            lacc += __logf(sc);
        }

        union { u32x4 u; short8 s; } c0, c1, c2, c3;
        c0.u = B0; c1.u = B1; c2.u = B2; c3.u = B3;
        f32x4 a0 = {0.f, 0.f, 0.f, 0.f}, a1 = {0.f, 0.f, 0.f, 0.f};
        a0 = MFMA16(Af[0][0], c0.s, a0); a1 = MFMA16(Af[1][0], c0.s, a1);
        a0 = MFMA16(Af[0][1], c1.s, a0); a1 = MFMA16(Af[1][1], c1.s, a1);
        a0 = MFMA16(Af[0][2], c2.s, a0); a1 = MFMA16(Af[1][2], c2.s, a1);
        a0 = MFMA16(Af[0][3], c3.s, a0); a1 = MFMA16(Af[1][3], c3.s, a1);

        const float mv = lo16f(Ew[0]);             // -1 sentinel = masked step
        float v0 = a0[0] * lo16f(Ew[0]), v1 = a0[1] * hi16f(Ew[0]);
        float v2 = a0[2] * lo16f(Ew[1]), v3 = a0[3] * hi16f(Ew[1]);
        float v4 = a1[0] * lo16f(Ew[2]), v5 = a1[1] * hi16f(Ew[2]);
        float v6 = a1[2] * lo16f(Ew[3]), v7 = a1[3] * hi16f(Ew[3]);
        if (AP) {
            v0 *= pendl; v1 *= pendl; v2 *= pendl; v3 *= pendl;
            v4 *= pendl; v5 *= pendl; v6 *= pendl; v7 *= pendl;
        }

        const u32x4 Bw = (w == 0) ? B0 : (w == 1) ? B1 : (w == 2) ? B2 : B3;

        if (t < TT - 1) {
            unsigned n0 = pk_trunc(v0, v1), n1 = pk_trunc(v2, v3);
            unsigned n2 = pk_trunc(v4, v5), n3 = pk_trunc(v6, v7);
            if (__ballot(mv < 0.f)) {              // rare keep-old path
                const bool msk = (mv < 0.f);
                unsigned k0 = pk_trunc(lo16f(Bw[0]) * pendl, hi16f(Bw[0]) * pendl);
                unsigned k1 = pk_trunc(lo16f(Bw[1]) * pendl, hi16f(Bw[1]) * pendl);
                unsigned k2 = pk_trunc(lo16f(Bw[2]) * pendl, hi16f(Bw[2]) * pendl);
                unsigned k3 = pk_trunc(lo16f(Bw[3]) * pendl, hi16f(Bw[3]) * pendl);
                n0 = msk ? k0 : n0; n1 = msk ? k1 : n1;
                n2 = msk ? k2 : n2; n3 = msk ? k3 : n3;
            }
            u32x4 nv; nv[0] = n0; nv[1] = n1; nv[2] = n2; nv[3] = n3;
            *(u32x4*)&st[t & 1][soff] = nv;
        } else {
            // t = 511: partial sum of this wave's 32 columns (pendl==1 here)
            float pn = v0 + v1 + v2 + v3 + v4 + v5 + v6 + v7;
            float po = lo16f(Bw[0]) + hi16f(Bw[0]) + lo16f(Bw[1]) + hi16f(Bw[1])
                     + lo16f(Bw[2]) + hi16f(Bw[2]) + lo16f(Bw[3]) + hi16f(Bw[3]);
            float pr = (mv < 0.f) ? po : pn;
            pr += __shfl_xor(pr, 16, 64);
            pr += __shfl_xor(pr, 32, 64);
            if (lane < 16) fsum[w][lane] = pr;
        }
        barrier_lgkm();
    }

    if (w == 0 && lane < 16) {
        float tot = fsum[0][lane] + fsum[1][lane] + fsum[2][lane] + fsum[3][lane];
        atomicAdd(&out[g * 16 + lane], __logf(tot) + lacc);
    }
}

// ---------------------------------------------------------------------------
extern "C" void kernel_launch(void* const* d_in, const int* in_sizes, int n_in,
                              void* d_out, int out_size, void* d_ws, size_t ws_size,
                              hipStream_t stream) {
    (void)in_sizes; (void)n_in; (void)out_size; (void)d_ws; (void)ws_size;
    const float* y_true = (const float*)d_in[0];
    const float* y_pred = (const float*)d_in[1];
    const float* mask   = (const float*)d_in[2];
    const float* trans  = (const float*)d_in[3];
    float* out = (float*)d_out;

    hipMemsetAsync(out, 0, BB * sizeof(float), stream);
    crf_all<<<dim3(8 + BB), 512, 0, stream>>>(y_true, y_pred, mask, trans, out);
}

// Round 10
// 436.501 us; speedup vs baseline: 1.3216x; 1.3216x over previous
//
#include <hip/hip_runtime.h>

#define BB 128
#define TT 512
#define CC 128

typedef short short8 __attribute__((ext_vector_type(8)));
typedef float f32x4  __attribute__((ext_vector_type(4)));
typedef unsigned u32x4 __attribute__((ext_vector_type(4)));

__device__ __forceinline__ unsigned pk_trunc(float a, float b) {
    // lo16 = trunc-bf16(a), hi16 = trunc-bf16(b); single v_perm (R5-verified)
    return __builtin_amdgcn_perm(__float_as_uint(a), __float_as_uint(b), 0x03020706u);
}
__device__ __forceinline__ unsigned short f2bf(float f) {   // RNE (E setup only)
    unsigned u = __float_as_uint(f);
    u += 0x7fffu + ((u >> 16) & 1u);
    return (unsigned short)(u >> 16);
}
__device__ __forceinline__ float lo16f(unsigned u) { return __uint_as_float(u << 16); }
__device__ __forceinline__ float hi16f(unsigned u) { return __uint_as_float(u & 0xffff0000u); }

#define MFMA16(A, B, C) __builtin_amdgcn_mfma_f32_16x16x32_bf16((A), (B), (C), 0, 0, 0)

// ---------------------------------------------------------------------------
// One fused kernel, 512 threads (8 waves) per block.
// Blocks 0..3  : scan, TWO groups per block. w0 = consumer group 2b,
//                w4 = consumer group 2b+1  -> both land on SIMD0 (i mod 4),
//                interleaving their MFMA streams to saturate the matrix pipe.
//                w1-3 / w5-7 = 3 loaders per group (steps t mod 3) streaming
//                bf16-packed exp(y_pred*mask) (-1 sentinel when masked) into a
//                per-group 16-slot LDS ring; R8's superslot handshake
//                (1 counter wait per 8 steps, back-pressure window 2).
// Blocks 4..131: real-path score, 8 waves x 64 rows; atomicAdd(-score).
// ---------------------------------------------------------------------------
__global__ __launch_bounds__(512, 1) void crf_all(
    const float* __restrict__ y_true, const float* __restrict__ y_pred,
    const float* __restrict__ mask, const float* __restrict__ trans,
    float* __restrict__ out)
{
    __shared__ __align__(16) unsigned ring[2][2][8][1024]; // [grp][S&1][step][..] 128KB
    __shared__ int cnt[2][2];                              // [grp][S&1]
    __shared__ int vcp[2];                                 // [grp] consumed superslot

    const int tid  = threadIdx.x;
    const int lane = tid & 63;
    const int w    = tid >> 6;

    if (blockIdx.x >= 4) {
        // ===================== real path (R3..R9-verified core) =============
        const int rb = blockIdx.x - 4;
        const int ts = w * 64;
        const int te = min(ts + 64, TT - 1);   // +1 overlap row
        const float* yt_b = y_true + (size_t)rb * TT * CC;
        const float* yp_b = y_pred + (size_t)rb * TT * CC;
        const float* m_b  = mask + (size_t)rb * TT;

        float em = 0.f, tr = 0.f;
        int lprev = 0; float mprev = 0.f;
        const float* ytr = yt_b + ts * CC;
        const float* ypr = yp_b + ts * CC;
        float cyt0 = ytr[lane], cyt1 = ytr[lane + 64];
        float cyp0 = ypr[lane], cyp1 = ypr[lane + 64];
        float cm = m_b[ts];
        for (int t = ts; t <= te; ++t) {
            float nyt0 = 0.f, nyt1 = 0.f, nyp0 = 0.f, nyp1 = 0.f, nm = 0.f;
            if (t < te) {
                const float* ytn = yt_b + (t + 1) * CC;
                const float* ypn = yp_b + (t + 1) * CC;
                nyt0 = ytn[lane]; nyt1 = ytn[lane + 64];
                nyp0 = ypn[lane]; nyp1 = ypn[lane + 64];
                nm = m_b[t + 1];
            }
            unsigned long long b0 = __ballot(cyt0 > 0.5f);
            unsigned long long b1 = __ballot(cyt1 > 0.5f);
            int l = b0 ? (__ffsll(b0) - 1) : (64 + __ffsll(b1) - 1);
            float v0 = __shfl(cyp0, l & 63);
            float v1 = __shfl(cyp1, l & 63);
            float v  = (l < 64) ? v0 : v1;
            if (lane == 0) {
                if (t < ts + 64) em += cm * cm * v;
                if (t > ts)      tr += mprev * cm * trans[lprev * CC + l];
            }
            lprev = l; mprev = cm;
            cyt0 = nyt0; cyt1 = nyt1; cyp0 = nyp0; cyp1 = nyp1; cm = nm;
        }
        if (lane == 0) atomicAdd(&out[rb], -(em + tr));
        return;
    }

    // ========================== scan blocks ==========================
    const int gp = w >> 2;                    // group-half within block (0/1)
    const int g  = blockIdx.x * 2 + gp;       // global group (16 batches)
    const int bq = lane & 15;
    const int q  = lane >> 4;

    volatile int* vgcnt = &cnt[gp][0];
    volatile int* vgcp  = &vcp[gp];

    if (w == 0) {
        if (lane < 2) { cnt[0][lane] = 0; cnt[1][lane] = 0; }
        if (lane == 2) { vcp[0] = -1; vcp[1] = -1; }
    }
    __syncthreads();   // scan blocks only; all 8 waves reach

    if ((w & 3) != 0) {
        // ================== loader wave (p = (w&3)-1, mod 3) ==============
        const int p = (w & 3) - 1;
        const float* ybase = y_pred + (size_t)(g * 16 + bq) * TT * CC;
        const float* mrow  = mask + (size_t)(g * 16 + bq) * TT;

        float4 va[8], vb[8]; float ma, mb = 0.f;
        {
            const float* r = ybase + (size_t)p * CC;
            #pragma unroll
            for (int c = 0; c < 8; ++c)
                va[c] = *(const float4*)(r + ((c >> 1) * 32 + q * 8 + (c & 1) * 4));
            ma = mrow[p];
        }
        for (int s = p; s < TT; s += 3) {
            if (s + 3 < TT) {                     // depth-2 load pipeline
                const float* r = ybase + (size_t)(s + 3) * CC;
                #pragma unroll
                for (int c = 0; c < 8; ++c)
                    vb[c] = *(const float4*)(r + ((c >> 1) * 32 + q * 8 + (c & 1) * 4));
                mb = mrow[s + 3];
            }
            const int S = s >> 3;
            while (*vgcp < S - 2) __builtin_amdgcn_s_sleep(8);   // back-pressure
            const bool live = (ma > 0.f) || (s == 0);
            unsigned pu[16];
            #pragma unroll
            for (int c = 0; c < 8; ++c) {
                float ex, ey, ez, ew;
                if (live) {
                    ex = __expf(va[c].x * ma); ey = __expf(va[c].y * ma);
                    ez = __expf(va[c].z * ma); ew = __expf(va[c].w * ma);
                } else { ex = ey = ez = ew = -1.0f; }
                pu[2 * c + 0] = pk_trunc(ex, ey);
                pu[2 * c + 1] = pk_trunc(ez, ew);
            }
            unsigned* dst = &ring[gp][S & 1][s & 7][0];
            #pragma unroll
            for (int k = 0; k < 4; ++k) {
                u32x4 wv;
                wv[0] = pu[4 * k + 0]; wv[1] = pu[4 * k + 1];
                wv[2] = pu[4 * k + 2]; wv[3] = pu[4 * k + 3];
                *(u32x4*)(dst + k * 256 + lane * 4) = wv;
            }
            __atomic_signal_fence(__ATOMIC_SEQ_CST);      // data before count
            if (lane == 0) atomicAdd((int*)&cnt[gp][S & 1], 1);
            #pragma unroll
            for (int c = 0; c < 8; ++c) va[c] = vb[c];
            ma = mb;
        }
        return;
    }

    // ================== consumer wave (w = 0 or 4; R8-identical) ============
    // A-frags: Af[nt][kt] = E^T tile with row perm sigma (R4-verified).
    short8 Af[8][4];
    #pragma unroll
    for (int nt = 0; nt < 8; ++nt) {
        const int j = 32 * (nt & 3) + 8 * (bq >> 2) + 4 * (nt >> 2) + (bq & 3);
        #pragma unroll
        for (int kt = 0; kt < 4; ++kt) {
            #pragma unroll
            for (int e = 0; e < 8; ++e)
                Af[nt][kt][e] = (short)f2bf(__expf(trans[(kt * 32 + q * 8 + e) * CC + j]));
        }
    }

    float pend = 1.f, lacc = 0.f;
    unsigned ps[16];          // packed bf16 state = next-step B-fragments

    auto dostep = [&](const unsigned* src, bool AP, bool RN) {
        u32x4 E[4];
        #pragma unroll
        for (int k = 0; k < 4; ++k)
            E[k] = *(const u32x4*)(src + k * 256 + lane * 4);
        short8 Bf[4];
        #pragma unroll
        for (int kt = 0; kt < 4; ++kt) {
            union { unsigned u[4]; short8 s; } bu;
            bu.u[0] = ps[4 * kt + 0]; bu.u[1] = ps[4 * kt + 1];
            bu.u[2] = ps[4 * kt + 2]; bu.u[3] = ps[4 * kt + 3];
            Bf[kt] = bu.s;
        }
        f32x4 acc[8];
        #pragma unroll
        for (int nt = 0; nt < 8; ++nt) {
            f32x4 a = {0.f, 0.f, 0.f, 0.f};
            a = MFMA16(Af[nt][0], Bf[0], a);
            a = MFMA16(Af[nt][1], Bf[1], a);
            a = MFMA16(Af[nt][2], Bf[2], a);
            a = MFMA16(Af[nt][3], Bf[3], a);
            acc[nt] = a;
        }
        const float mv = lo16f(E[0][0]);        // -1 sentinel = masked step
        float val[8][4];
        #pragma unroll
        for (int nt = 0; nt < 8; ++nt) {
            const int c = 2 * (nt & 3) + (nt >> 2);
            const unsigned plo = E[(2 * c) >> 2][(2 * c) & 3];
            const unsigned phi = E[(2 * c + 1) >> 2][(2 * c + 1) & 3];
            val[nt][0] = acc[nt][0] * lo16f(plo);
            val[nt][1] = acc[nt][1] * hi16f(plo);
            val[nt][2] = acc[nt][2] * lo16f(phi);
            val[nt][3] = acc[nt][3] * hi16f(phi);
            if (AP) {
                val[nt][0] *= pend; val[nt][1] *= pend;
                val[nt][2] *= pend; val[nt][3] *= pend;
            }
        }
        unsigned nps[16];
        #pragma unroll
        for (int nt = 0; nt < 8; ++nt) {
            const int kt = nt & 3, h = nt >> 2;
            nps[kt * 4 + 2 * h + 0] = pk_trunc(val[nt][0], val[nt][1]);
            nps[kt * 4 + 2 * h + 1] = pk_trunc(val[nt][2], val[nt][3]);
        }
        if (__ballot(mv < 0.f)) {               // rare keep-old path
            #pragma unroll
            for (int p2 = 0; p2 < 16; ++p2) {
                unsigned kept = pk_trunc(lo16f(ps[p2]) * pend, hi16f(ps[p2]) * pend);
                nps[p2] = (mv < 0.f) ? kept : nps[p2];
            }
        }
        #pragma unroll
        for (int p2 = 0; p2 < 16; ++p2) ps[p2] = nps[p2];
        if (AP) pend = 1.f;
        if (RN) {
            float s2 = lo16f(ps[0]);
            float bc = __shfl(s2, bq, 64);
            pend = __builtin_amdgcn_rcpf(bc);
            lacc += __logf(bc);
        }
    };

    // -------- superslot 0: t=0 init + steps 1..7 --------
    while (vgcnt[0] != 8) __builtin_amdgcn_s_sleep(2);
    __atomic_signal_fence(__ATOMIC_SEQ_CST);
    {
        const unsigned* src = &ring[gp][0][0][0];
        #pragma unroll
        for (int k = 0; k < 4; ++k) {
            u32x4 e0 = *(const u32x4*)(src + k * 256 + lane * 4);
            ps[4 * k + 0] = e0[0]; ps[4 * k + 1] = e0[1];
            ps[4 * k + 2] = e0[2]; ps[4 * k + 3] = e0[3];
        }
    }
    dostep(&ring[gp][0][1][0], true,  false);
    dostep(&ring[gp][0][2][0], false, false);
    dostep(&ring[gp][0][3][0], false, false);
    dostep(&ring[gp][0][4][0], false, true);
    dostep(&ring[gp][0][5][0], true,  false);
    dostep(&ring[gp][0][6][0], false, false);
    dostep(&ring[gp][0][7][0], false, false);
    cnt[gp][0] = 0;
    __atomic_signal_fence(__ATOMIC_SEQ_CST);
    *vgcp = 0;

    // -------- superslots 1..62: 8 steps each --------
    for (int S = 1; S < 63; ++S) {
        const int sl = S & 1;
        while (vgcnt[sl] != 8) __builtin_amdgcn_s_sleep(2);
        __atomic_signal_fence(__ATOMIC_SEQ_CST);
        dostep(&ring[gp][sl][0][0], false, true);
        dostep(&ring[gp][sl][1][0], true,  false);
        dostep(&ring[gp][sl][2][0], false, false);
        dostep(&ring[gp][sl][3][0], false, false);
        dostep(&ring[gp][sl][4][0], false, true);
        dostep(&ring[gp][sl][5][0], true,  false);
        dostep(&ring[gp][sl][6][0], false, false);
        dostep(&ring[gp][sl][7][0], false, false);
        cnt[gp][sl] = 0;
        __atomic_signal_fence(__ATOMIC_SEQ_CST);
        *vgcp = S;
    }

    // -------- superslot 63: steps 504..510, then final-sum t=511 --------
    while (vgcnt[1] != 8) __builtin_amdgcn_s_sleep(2);
    __atomic_signal_fence(__ATOMIC_SEQ_CST);
    dostep(&ring[gp][1][0][0], false, true);
    dostep(&ring[gp][1][1][0], true,  false);
    dostep(&ring[gp][1][2][0], false, false);
    dostep(&ring[gp][1][3][0], false, false);
    dostep(&ring[gp][1][4][0], false, true);
    dostep(&ring[gp][1][5][0], true,  false);
    dostep(&ring[gp][1][6][0], false, false);
    {
        const unsigned* src = &ring[gp][1][7][0];
        u32x4 E[4];
        #pragma unroll
        for (int k = 0; k < 4; ++k)
            E[k] = *(const u32x4*)(src + k * 256 + lane * 4);
        short8 Bf[4];
        #pragma unroll
        for (int kt = 0; kt < 4; ++kt) {
            union { unsigned u[4]; short8 s; } bu;
            bu.u[0] = ps[4 * kt + 0]; bu.u[1] = ps[4 * kt + 1];
            bu.u[2] = ps[4 * kt + 2]; bu.u[3] = ps[4 * kt + 3];
            Bf[kt] = bu.s;
        }
        float ssum = 0.f;
        const float mv = lo16f(E[0][0]);
        #pragma unroll
        for (int nt = 0; nt < 8; ++nt) {
            f32x4 a = {0.f, 0.f, 0.f, 0.f};
            a = MFMA16(Af[nt][0], Bf[0], a);
            a = MFMA16(Af[nt][1], Bf[1], a);
            a = MFMA16(Af[nt][2], Bf[2], a);
            a = MFMA16(Af[nt][3], Bf[3], a);
            const int c = 2 * (nt & 3) + (nt >> 2);
            const unsigned plo = E[(2 * c) >> 2][(2 * c) & 3];
            const unsigned phi = E[(2 * c + 1) >> 2][(2 * c + 1) & 3];
            ssum += a[0] * lo16f(plo) + a[1] * hi16f(plo)
                  + a[2] * lo16f(phi) + a[3] * hi16f(phi);
        }
        if (__ballot(mv < 0.f)) {
            float os = 0.f;
            #pragma unroll
            for (int p2 = 0; p2 < 16; ++p2) os += lo16f(ps[p2]) + hi16f(ps[p2]);
            ssum = (mv < 0.f) ? os : ssum;   // pend == 1 here (511 % 4 == 3)
        }
        ssum += __shfl_xor(ssum, 16, 64);
        ssum += __shfl_xor(ssum, 32, 64);
        if (lane < 16) atomicAdd(&out[g * 16 + lane], __logf(ssum) + lacc);
    }
}

// ---------------------------------------------------------------------------
extern "C" void kernel_launch(void* const* d_in, const int* in_sizes, int n_in,
                              void* d_out, int out_size, void* d_ws, size_t ws_size,
                              hipStream_t stream) {
    (void)in_sizes; (void)n_in; (void)out_size; (void)d_ws; (void)ws_size;
    const float* y_true = (const float*)d_in[0];
    const float* y_pred = (const float*)d_in[1];
    const float* mask   = (const float*)d_in[2];
    const float* trans  = (const float*)d_in[3];
    float* out = (float*)d_out;

    hipMemsetAsync(out, 0, BB * sizeof(float), stream);
    crf_all<<<dim3(4 + BB), 512, 0, stream>>>(y_true, y_pred, mask, trans, out);
}